// Round 4
// baseline (622.465 us; speedup 1.0000x reference)
//
#include <hip/hip_runtime.h>
#include <math.h>
#include <stdint.h>

#define N_PTS 2048
#define I_DIM 16
#define H_DIM 64
#define O_DIM 64
#define NCUTS 8
#define NGROUPS 4
#define GN_EPS 1e-5f

typedef __attribute__((ext_vector_type(8))) short short8;
typedef __attribute__((ext_vector_type(4))) float f32x4;
typedef __attribute__((ext_vector_type(4))) uint32_t u32x4;

__device__ inline uint32_t cvt_pk_bf16(float lo, float hi) {
    uint32_t r;
    asm("v_cvt_pk_bf16_f32 %0, %1, %2" : "=v"(r) : "v"(lo), "v"(hi));
    return r;
}

__device__ inline short8 frag_of(uint32_t a, uint32_t b, uint32_t c, uint32_t d) {
    u32x4 t; t.x = a; t.y = b; t.z = c; t.w = d;
    return __builtin_bit_cast(short8, t);
}

// ---------------------------------------------------------------------------
// k1: input MLP  f = lrelu(lrelu(features @ W1^T + b1) @ W2^T + b2)
// ---------------------------------------------------------------------------
__global__ __launch_bounds__(256) void k_in_mlp(
    const float* __restrict__ features, const float* __restrict__ W1,
    const float* __restrict__ b1, const float* __restrict__ W2,
    const float* __restrict__ b2, float* __restrict__ out)
{
    __shared__ float f0s[4][H_DIM];
    int tid = threadIdx.x;
    int pl = tid >> 6, h = tid & 63;
    int n = blockIdx.x * 4 + pl;
    const float* fr = features + n * I_DIM;
    float s = b1[h];
    #pragma unroll
    for (int i = 0; i < I_DIM; ++i) s = fmaf(fr[i], W1[h * I_DIM + i], s);
    s = s > 0.f ? s : 0.2f * s;
    f0s[pl][h] = s;
    __syncthreads();
    float t = b2[h];
    #pragma unroll
    for (int k = 0; k < H_DIM; ++k) t = fmaf(f0s[pl][k], W2[h * H_DIM + k], t);
    t = t > 0.f ? t : 0.2f * t;
    out[n * H_DIM + h] = t;
}

// ---------------------------------------------------------------------------
// k2: group norm over (channels_in_group x ALL points), 1 block per group.
// ---------------------------------------------------------------------------
__global__ __launch_bounds__(1024) void k_gnorm(
    const float* __restrict__ x, const float* __restrict__ w,
    const float* __restrict__ b, float* __restrict__ out)
{
    const int CPG = H_DIM / NGROUPS;          // 16
    const int TOT = CPG * N_PTS;              // 32768
    int g = blockIdx.x;
    int tid = threadIdx.x;
    float sum = 0.f, sq = 0.f;
    for (int idx = tid; idx < TOT; idx += 1024) {
        int ch = g * CPG + (idx & (CPG - 1));
        int n  = idx >> 4;
        float v = x[n * H_DIM + ch];
        sum += v; sq += v * v;
    }
    #pragma unroll
    for (int off = 32; off >= 1; off >>= 1) {
        sum += __shfl_down(sum, off);
        sq  += __shfl_down(sq , off);
    }
    __shared__ float ssum[16], ssq[16];
    __shared__ float mean_s, rstd_s;
    int lane = tid & 63, wv = tid >> 6;
    if (lane == 0) { ssum[wv] = sum; ssq[wv] = sq; }
    __syncthreads();
    if (tid == 0) {
        float S = 0.f, Q = 0.f;
        #pragma unroll
        for (int i = 0; i < 16; ++i) { S += ssum[i]; Q += ssq[i]; }
        float m   = S / (float)TOT;
        float var = Q / (float)TOT - m * m;
        mean_s = m;
        rstd_s = rsqrtf(var + GN_EPS);
    }
    __syncthreads();
    float m = mean_s, r = rstd_s;
    for (int idx = tid; idx < TOT; idx += 1024) {
        int ch = g * CPG + (idx & (CPG - 1));
        int n  = idx >> 4;
        float v = x[n * H_DIM + ch];
        out[n * H_DIM + ch] = (v - m) * r * w[ch] + b[ch];
    }
}

// ---------------------------------------------------------------------------
// k3: pairwise windowed conv via MFMA, LAYOUT-SELF-CALIBRATING.
// Orientation: D(ch_tile, j_tile) = A(ch, k) * B(k, j)
//   A[ch, c<8] = w2[ch][c], A[ch, 8] = b2[ch]   (const regs, bf16)
//   B[c<8, j]  = win*h[j][c], B[8, j] = win(j)
// Probe MFMAs discover, for each (lane, reg), which (ch-offset cc, j-offset jj)
// of the 16x16 D tile landed there. All pairing (f-loads, red writes) uses
// probed cc/jj -> correct under ANY bijective symmetric operand layout.
// out[i,ch] = sum_j relu(D[ch,j]) * f[j][ch].
// ---------------------------------------------------------------------------
__global__ __launch_bounds__(256) void k_conv_mfma(
    const float* __restrict__ points, const float* __restrict__ nuv,
    const float* __restrict__ cw1, const float* __restrict__ cb1,
    const float* __restrict__ cw2, const float* __restrict__ cb2,
    const float* __restrict__ fn, float* __restrict__ out)
{
    const float SC = 0.70710678118654752f;   // 1/sqrt(2), RADIUS=1
    int i   = blockIdx.x;
    int tid = threadIdx.x;
    int lane = tid & 63, wv = tid >> 6;
    int l15 = lane & 15, lg = lane >> 4;

    // ---- layout probes -------------------------------------------------
    // probe1: A[row][k0] = intended row index (l15), B[k0][col] = 1
    //         -> D[(lane,reg)] = ch-offset that landed here (cc)
    // probe2: A[row][k0] = 1, B[k0][col] = intended col index (l15)
    //         -> D[(lane,reg)] = j-offset that landed here (jj)
    uint32_t one_b = cvt_pk_bf16(1.f, 0.f);
    uint32_t idx_b = cvt_pk_bf16((float)l15, 0.f);
    short8 pIdx = frag_of(lg == 0 ? idx_b : 0u, 0u, 0u, 0u);
    short8 pOne = frag_of(lg == 0 ? one_b : 0u, 0u, 0u, 0u);
    f32x4 Dc = __builtin_amdgcn_mfma_f32_16x16x32_bf16(
        pIdx, pOne, (f32x4){0.f, 0.f, 0.f, 0.f}, 0, 0, 0);
    f32x4 Dj = __builtin_amdgcn_mfma_f32_16x16x32_bf16(
        pOne, pIdx, (f32x4){0.f, 0.f, 0.f, 0.f}, 0, 0, 0);
    int cc[4], jj[4];
    #pragma unroll
    for (int r = 0; r < 4; ++r) {
        cc[r] = (int)(Dc[r] + 0.5f);
        jj[r] = (int)(Dj[r] + 0.5f);
    }

    // ---- per-block (uniform) point-i data ------------------------------
    float pix = points[i * 3 + 0] * SC;
    float piy = points[i * 3 + 1] * SC;
    float piz = points[i * 3 + 2] * SC;
    float nv[9];
    #pragma unroll
    for (int a = 0; a < 9; ++a) nv[a] = nuv[i * 9 + a];
    float w1c[NCUTS][3], bb1[NCUTS];
    #pragma unroll
    for (int c = 0; c < NCUTS; ++c) {
        w1c[c][0] = cw1[c * 3 + 0];
        w1c[c][1] = cw1[c * 3 + 1];
        w1c[c][2] = cw1[c * 3 + 2];
        bb1[c]    = cb1[c];
    }

    // ---- constant A-frags: tile m covers ch = m*16 + (0..15) -----------
    short8 Af[4];
    #pragma unroll
    for (int m = 0; m < 4; ++m) {
        int ch = m * 16 + l15;
        uint32_t a0 = 0, a1 = 0, a2 = 0, a3 = 0;
        if (lg == 0) {
            a0 = cvt_pk_bf16(cw2[ch * 8 + 0], cw2[ch * 8 + 1]);
            a1 = cvt_pk_bf16(cw2[ch * 8 + 2], cw2[ch * 8 + 3]);
            a2 = cvt_pk_bf16(cw2[ch * 8 + 4], cw2[ch * 8 + 5]);
            a3 = cvt_pk_bf16(cw2[ch * 8 + 6], cw2[ch * 8 + 7]);
        } else if (lg == 1) {
            a0 = cvt_pk_bf16(cb2[ch], 0.f);   // k=8 slot: bias row
        }
        Af[m] = frag_of(a0, a1, a2, a3);
    }

    float acc[4][4];
    #pragma unroll
    for (int m = 0; m < 4; ++m)
        #pragma unroll
        for (int r = 0; r < 4; ++r) acc[m][r] = 0.f;

    #pragma unroll 1
    for (int jt = wv; jt < N_PTS / 64; jt += 4) {
        int j = jt * 64 + lane;
        float dx = points[j * 3 + 0] * SC - pix;
        float dy = points[j * 3 + 1] * SC - piy;
        float dz = points[j * 3 + 2] * SC - piz;
        float njx = nuv[j * 9 + 0], njy = nuv[j * 9 + 1], njz = nuv[j * 9 + 2];
        float nd = nv[0] * njx + nv[1] * njy + nv[2] * njz;
        float tt = 2.f - nd;
        float d2 = (dx * dx + dy * dy + dz * dz) * tt * tt;
        float win = __expf(-d2);
        float P0 = nv[0] * dx + nv[1] * dy + nv[2] * dz;
        float P1 = nv[3] * dx + nv[4] * dy + nv[5] * dz;
        float P2 = nv[6] * dx + nv[7] * dy + nv[8] * dz;
        float hp[NCUTS];
        #pragma unroll
        for (int c = 0; c < NCUTS; ++c) {
            float v = fmaf(P0, w1c[c][0], fmaf(P1, w1c[c][1], fmaf(P2, w1c[c][2], bb1[c])));
            v = v > 0.f ? v : 0.f;
            hp[c] = win * v;                  // fold window into B
        }
        uint32_t hw0 = cvt_pk_bf16(hp[0], hp[1]);
        uint32_t hw1 = cvt_pk_bf16(hp[2], hp[3]);
        uint32_t hw2 = cvt_pk_bf16(hp[4], hp[5]);
        uint32_t hw3 = cvt_pk_bf16(hp[6], hp[7]);
        uint32_t ww  = cvt_pk_bf16(win, 0.f); // k=8 slot: window (x b2)

        const float* fbase = fn + (size_t)jt * 64 * H_DIM;

        #pragma unroll
        for (int n = 0; n < 4; ++n) {
            int src = n * 16 + l15;           // j whose h' this lane carries
            uint32_t s0 = (uint32_t)__shfl((int)hw0, src);
            uint32_t s1 = (uint32_t)__shfl((int)hw1, src);
            uint32_t s2 = (uint32_t)__shfl((int)hw2, src);
            uint32_t s3 = (uint32_t)__shfl((int)hw3, src);
            uint32_t sw = (uint32_t)__shfl((int)ww , src);
            short8 Bf = frag_of(
                (lg == 0) ? s0 : ((lg == 1) ? sw : 0u),
                (lg == 0) ? s1 : 0u,
                (lg == 0) ? s2 : 0u,
                (lg == 0) ? s3 : 0u);
            #pragma unroll
            for (int m = 0; m < 4; ++m) {
                f32x4 C = __builtin_amdgcn_mfma_f32_16x16x32_bf16(
                    Af[m], Bf, (f32x4){0.f, 0.f, 0.f, 0.f}, 0, 0, 0);
                #pragma unroll
                for (int r = 0; r < 4; ++r) {
                    float x = C[r] > 0.f ? C[r] : 0.f;
                    // probed pairing: this (lane,reg) holds (ch=m*16+cc[r], j=n*16+jj[r])
                    float fval = fbase[(n * 16 + jj[r]) * H_DIM + m * 16 + cc[r]];
                    acc[m][r] = fmaf(x, fval, acc[m][r]);
                }
            }
        }
    }

    // reduce over the 16 j-columns held across l15 (butterfly -> all lanes)
    #pragma unroll
    for (int m = 0; m < 4; ++m)
        #pragma unroll
        for (int r = 0; r < 4; ++r) {
            float v = acc[m][r];
            v += __shfl_xor(v, 1);
            v += __shfl_xor(v, 2);
            v += __shfl_xor(v, 4);
            v += __shfl_xor(v, 8);
            acc[m][r] = v;
        }

    __shared__ float red[4][H_DIM];
    if (l15 == 0) {
        #pragma unroll
        for (int m = 0; m < 4; ++m)
            #pragma unroll
            for (int r = 0; r < 4; ++r)
                red[wv][m * 16 + cc[r]] = acc[m][r];
    }
    __syncthreads();
    if (tid < H_DIM) {
        out[i * H_DIM + tid] = red[0][tid] + red[1][tid] + red[2][tid] + red[3][tid];
    }
}

// ---------------------------------------------------------------------------
// k4: output MLP
// ---------------------------------------------------------------------------
__global__ __launch_bounds__(256) void k_out_mlp(
    const float* __restrict__ fin, const float* __restrict__ W1,
    const float* __restrict__ b1, const float* __restrict__ W2,
    const float* __restrict__ b2, float* __restrict__ out)
{
    __shared__ float t1s[4][O_DIM];
    int tid = threadIdx.x;
    int pl = tid >> 6, o = tid & 63;
    int n = blockIdx.x * 4 + pl;
    const float* fr = fin + n * H_DIM;
    float s = b1[o];
    #pragma unroll
    for (int k = 0; k < H_DIM; ++k) s = fmaf(fr[k], W1[o * H_DIM + k], s);
    s = s > 0.f ? s : 0.2f * s;
    t1s[pl][o] = s;
    __syncthreads();
    float t = b2[o];
    #pragma unroll
    for (int k = 0; k < O_DIM; ++k) t = fmaf(t1s[pl][k], W2[o * O_DIM + k], t);
    t = t > 0.f ? t : 0.2f * t;
    out[n * O_DIM + o] = t;
}

// ---------------------------------------------------------------------------
extern "C" void kernel_launch(void* const* d_in, const int* in_sizes, int n_in,
                              void* d_out, int out_size, void* d_ws, size_t ws_size,
                              hipStream_t stream)
{
    const float* points   = (const float*)d_in[0];
    const float* nuv      = (const float*)d_in[1];
    const float* features = (const float*)d_in[2];
    const float* W_in1    = (const float*)d_in[3];
    const float* b_in1    = (const float*)d_in[4];
    const float* W_in2    = (const float*)d_in[5];
    const float* b_in2    = (const float*)d_in[6];
    const float* gn_in_w  = (const float*)d_in[7];
    const float* gn_in_b  = (const float*)d_in[8];
    const float* cw1      = (const float*)d_in[9];
    const float* cb1      = (const float*)d_in[10];
    const float* cw2      = (const float*)d_in[11];
    const float* cb2      = (const float*)d_in[12];
    const float* W_out1   = (const float*)d_in[13];
    const float* b_out1   = (const float*)d_in[14];
    const float* W_out2   = (const float*)d_in[15];
    const float* b_out2   = (const float*)d_in[16];
    const float* gn_out_w = (const float*)d_in[17];
    const float* gn_out_b = (const float*)d_in[18];

    float* bufA = (float*)d_ws;                // N*64 floats
    float* bufB = bufA + N_PTS * H_DIM;        // N*64 floats
    float* outp = (float*)d_out;

    k_in_mlp    <<<N_PTS / 4, 256, 0, stream>>>(features, W_in1, b_in1, W_in2, b_in2, bufA);
    k_gnorm     <<<NGROUPS, 1024, 0, stream>>>(bufA, gn_in_w, gn_in_b, bufB);
    k_conv_mfma <<<N_PTS, 256, 0, stream>>>(points, nuv, cw1, cb1, cw2, cb2, bufB, bufA);
    k_out_mlp   <<<N_PTS / 4, 256, 0, stream>>>(bufA, W_out1, b_out1, W_out2, b_out2, bufB);
    k_gnorm     <<<NGROUPS, 1024, 0, stream>>>(bufB, gn_out_w, gn_out_b, outp);
}

// Round 5
// 601.778 us; speedup vs baseline: 1.0344x; 1.0344x over previous
//
#include <hip/hip_runtime.h>
#include <math.h>
#include <stdint.h>

#define N_PTS 2048
#define I_DIM 16
#define H_DIM 64
#define O_DIM 64
#define NCUTS 8
#define NGROUPS 4
#define GN_EPS 1e-5f

typedef __attribute__((ext_vector_type(8))) short short8;
typedef __attribute__((ext_vector_type(4))) float f32x4;
typedef __attribute__((ext_vector_type(4))) uint32_t u32x4;

__device__ inline uint32_t cvt_pk_bf16(float lo, float hi) {
    uint32_t r;
    asm("v_cvt_pk_bf16_f32 %0, %1, %2" : "=v"(r) : "v"(lo), "v"(hi));
    return r;
}

__device__ inline short8 frag_of(uint32_t a, uint32_t b, uint32_t c, uint32_t d) {
    u32x4 t; t.x = a; t.y = b; t.z = c; t.w = d;
    return __builtin_bit_cast(short8, t);
}

// ---------------------------------------------------------------------------
// k1: input MLP  f = lrelu(lrelu(features @ W1^T + b1) @ W2^T + b2)
// ---------------------------------------------------------------------------
__global__ __launch_bounds__(256) void k_in_mlp(
    const float* __restrict__ features, const float* __restrict__ W1,
    const float* __restrict__ b1, const float* __restrict__ W2,
    const float* __restrict__ b2, float* __restrict__ out)
{
    __shared__ float f0s[4][H_DIM];
    int tid = threadIdx.x;
    int pl = tid >> 6, h = tid & 63;
    int n = blockIdx.x * 4 + pl;
    const float* fr = features + n * I_DIM;
    float s = b1[h];
    #pragma unroll
    for (int i = 0; i < I_DIM; ++i) s = fmaf(fr[i], W1[h * I_DIM + i], s);
    s = s > 0.f ? s : 0.2f * s;
    f0s[pl][h] = s;
    __syncthreads();
    float t = b2[h];
    #pragma unroll
    for (int k = 0; k < H_DIM; ++k) t = fmaf(f0s[pl][k], W2[h * H_DIM + k], t);
    t = t > 0.f ? t : 0.2f * t;
    out[n * H_DIM + h] = t;
}

// ---------------------------------------------------------------------------
// k2: group norm over (channels_in_group x ALL points), 1 block per group.
// ---------------------------------------------------------------------------
__global__ __launch_bounds__(1024) void k_gnorm(
    const float* __restrict__ x, const float* __restrict__ w,
    const float* __restrict__ b, float* __restrict__ out)
{
    const int CPG = H_DIM / NGROUPS;          // 16
    const int TOT = CPG * N_PTS;              // 32768
    int g = blockIdx.x;
    int tid = threadIdx.x;
    float sum = 0.f, sq = 0.f;
    for (int idx = tid; idx < TOT; idx += 1024) {
        int ch = g * CPG + (idx & (CPG - 1));
        int n  = idx >> 4;
        float v = x[n * H_DIM + ch];
        sum += v; sq += v * v;
    }
    #pragma unroll
    for (int off = 32; off >= 1; off >>= 1) {
        sum += __shfl_down(sum, off);
        sq  += __shfl_down(sq , off);
    }
    __shared__ float ssum[16], ssq[16];
    __shared__ float mean_s, rstd_s;
    int lane = tid & 63, wv = tid >> 6;
    if (lane == 0) { ssum[wv] = sum; ssq[wv] = sq; }
    __syncthreads();
    if (tid == 0) {
        float S = 0.f, Q = 0.f;
        #pragma unroll
        for (int i = 0; i < 16; ++i) { S += ssum[i]; Q += ssq[i]; }
        float m   = S / (float)TOT;
        float var = Q / (float)TOT - m * m;
        mean_s = m;
        rstd_s = rsqrtf(var + GN_EPS);
    }
    __syncthreads();
    float m = mean_s, r = rstd_s;
    for (int idx = tid; idx < TOT; idx += 1024) {
        int ch = g * CPG + (idx & (CPG - 1));
        int n  = idx >> 4;
        float v = x[n * H_DIM + ch];
        out[n * H_DIM + ch] = (v - m) * r * w[ch] + b[ch];
    }
}

// ---------------------------------------------------------------------------
// k3: pairwise windowed conv via MFMA, shfl-free inner loop.
// D(ch, j) = A(ch, k) * B(k, j);  A = (w2 | b2) const regs,
// B built per 16-j sub-tile DIRECTLY: lane (lg,l15) computes the preamble
// for j = jt*64 + n*16 + l15 itself (redundant across lg groups; no shfl,
// no lgkmcnt stalls). Probed cc/jj pairing (passed R4) kept for f-loads
// and the final red[] write.
// out[i,ch] = sum_j relu(D[ch,j]) * f[j][ch].
// ---------------------------------------------------------------------------
__global__ __launch_bounds__(256) void k_conv_mfma(
    const float* __restrict__ points, const float* __restrict__ nuv,
    const float* __restrict__ cw1, const float* __restrict__ cb1,
    const float* __restrict__ cw2, const float* __restrict__ cb2,
    const float* __restrict__ fn, float* __restrict__ out)
{
    const float SC = 0.70710678118654752f;   // 1/sqrt(2), RADIUS=1
    int i   = blockIdx.x;
    int tid = threadIdx.x;
    int lane = tid & 63, wv = tid >> 6;
    int l15 = lane & 15, lg = lane >> 4;

    // ---- layout probes (unchanged from R4 — verified PASS) -------------
    uint32_t one_b = cvt_pk_bf16(1.f, 0.f);
    uint32_t idx_b = cvt_pk_bf16((float)l15, 0.f);
    short8 pIdx = frag_of(lg == 0 ? idx_b : 0u, 0u, 0u, 0u);
    short8 pOne = frag_of(lg == 0 ? one_b : 0u, 0u, 0u, 0u);
    f32x4 Dc = __builtin_amdgcn_mfma_f32_16x16x32_bf16(
        pIdx, pOne, (f32x4){0.f, 0.f, 0.f, 0.f}, 0, 0, 0);
    f32x4 Dj = __builtin_amdgcn_mfma_f32_16x16x32_bf16(
        pOne, pIdx, (f32x4){0.f, 0.f, 0.f, 0.f}, 0, 0, 0);
    int cc[4], foff[4];
    #pragma unroll
    for (int r = 0; r < 4; ++r) {
        cc[r] = (int)(Dc[r] + 0.5f);
        int jjr = (int)(Dj[r] + 0.5f);
        foff[r] = jjr * H_DIM + cc[r];        // loop-invariant f-offset
    }

    // ---- per-block (uniform) point-i data ------------------------------
    float pix = points[i * 3 + 0] * SC;
    float piy = points[i * 3 + 1] * SC;
    float piz = points[i * 3 + 2] * SC;
    float nv[9];
    #pragma unroll
    for (int a = 0; a < 9; ++a) nv[a] = nuv[i * 9 + a];
    float w1c[NCUTS][3], bb1[NCUTS];
    #pragma unroll
    for (int c = 0; c < NCUTS; ++c) {
        w1c[c][0] = cw1[c * 3 + 0];
        w1c[c][1] = cw1[c * 3 + 1];
        w1c[c][2] = cw1[c * 3 + 2];
        bb1[c]    = cb1[c];
    }

    // ---- constant A-frags: tile m covers ch = m*16 + (0..15) -----------
    short8 Af[4];
    #pragma unroll
    for (int m = 0; m < 4; ++m) {
        int ch = m * 16 + l15;
        uint32_t a0 = 0, a1 = 0, a2 = 0, a3 = 0;
        if (lg == 0) {
            a0 = cvt_pk_bf16(cw2[ch * 8 + 0], cw2[ch * 8 + 1]);
            a1 = cvt_pk_bf16(cw2[ch * 8 + 2], cw2[ch * 8 + 3]);
            a2 = cvt_pk_bf16(cw2[ch * 8 + 4], cw2[ch * 8 + 5]);
            a3 = cvt_pk_bf16(cw2[ch * 8 + 6], cw2[ch * 8 + 7]);
        } else if (lg == 1) {
            a0 = cvt_pk_bf16(cb2[ch], 0.f);   // k=8 slot: bias row
        }
        Af[m] = frag_of(a0, a1, a2, a3);
    }

    float acc[4][4];
    #pragma unroll
    for (int m = 0; m < 4; ++m)
        #pragma unroll
        for (int r = 0; r < 4; ++r) acc[m][r] = 0.f;

    #pragma unroll 1
    for (int jt = wv; jt < N_PTS / 64; jt += 4) {
        const float* fbase = fn + (size_t)jt * 64 * H_DIM;
        #pragma unroll
        for (int n = 0; n < 4; ++n) {
            // this lane computes the preamble for the j-column it feeds
            int j = jt * 64 + n * 16 + l15;
            float dx = points[j * 3 + 0] * SC - pix;
            float dy = points[j * 3 + 1] * SC - piy;
            float dz = points[j * 3 + 2] * SC - piz;
            float njx = nuv[j * 9 + 0], njy = nuv[j * 9 + 1], njz = nuv[j * 9 + 2];
            float nd = nv[0] * njx + nv[1] * njy + nv[2] * njz;
            float tt = 2.f - nd;
            float d2 = (dx * dx + dy * dy + dz * dz) * tt * tt;
            float win = __expf(-d2);
            float P0 = nv[0] * dx + nv[1] * dy + nv[2] * dz;
            float P1 = nv[3] * dx + nv[4] * dy + nv[5] * dz;
            float P2 = nv[6] * dx + nv[7] * dy + nv[8] * dz;
            float hp[NCUTS];
            #pragma unroll
            for (int c = 0; c < NCUTS; ++c) {
                float v = fmaf(P0, w1c[c][0], fmaf(P1, w1c[c][1], fmaf(P2, w1c[c][2], bb1[c])));
                v = v > 0.f ? v : 0.f;
                hp[c] = win * v;              // fold window into B
            }
            uint32_t hw0 = cvt_pk_bf16(hp[0], hp[1]);
            uint32_t hw1 = cvt_pk_bf16(hp[2], hp[3]);
            uint32_t hw2 = cvt_pk_bf16(hp[4], hp[5]);
            uint32_t hw3 = cvt_pk_bf16(hp[6], hp[7]);
            uint32_t ww  = cvt_pk_bf16(win, 0.f);
            short8 Bf = frag_of(
                (lg == 0) ? hw0 : ((lg == 1) ? ww : 0u),
                (lg == 0) ? hw1 : 0u,
                (lg == 0) ? hw2 : 0u,
                (lg == 0) ? hw3 : 0u);
            const float* fsub = fbase + n * 16 * H_DIM;
            #pragma unroll
            for (int m = 0; m < 4; ++m) {
                f32x4 C = __builtin_amdgcn_mfma_f32_16x16x32_bf16(
                    Af[m], Bf, (f32x4){0.f, 0.f, 0.f, 0.f}, 0, 0, 0);
                #pragma unroll
                for (int r = 0; r < 4; ++r) {
                    float x = C[r] > 0.f ? C[r] : 0.f;
                    float fval = fsub[m * 16 + foff[r]];
                    acc[m][r] = fmaf(x, fval, acc[m][r]);
                }
            }
        }
    }

    // reduce over the 16 j-columns held across l15 (butterfly -> all lanes)
    #pragma unroll
    for (int m = 0; m < 4; ++m)
        #pragma unroll
        for (int r = 0; r < 4; ++r) {
            float v = acc[m][r];
            v += __shfl_xor(v, 1);
            v += __shfl_xor(v, 2);
            v += __shfl_xor(v, 4);
            v += __shfl_xor(v, 8);
            acc[m][r] = v;
        }

    __shared__ float red[4][H_DIM];
    if (l15 == 0) {
        #pragma unroll
        for (int m = 0; m < 4; ++m)
            #pragma unroll
            for (int r = 0; r < 4; ++r)
                red[wv][m * 16 + cc[r]] = acc[m][r];
    }
    __syncthreads();
    if (tid < H_DIM) {
        out[i * H_DIM + tid] = red[0][tid] + red[1][tid] + red[2][tid] + red[3][tid];
    }
}

// ---------------------------------------------------------------------------
// k4: output MLP
// ---------------------------------------------------------------------------
__global__ __launch_bounds__(256) void k_out_mlp(
    const float* __restrict__ fin, const float* __restrict__ W1,
    const float* __restrict__ b1, const float* __restrict__ W2,
    const float* __restrict__ b2, float* __restrict__ out)
{
    __shared__ float t1s[4][O_DIM];
    int tid = threadIdx.x;
    int pl = tid >> 6, o = tid & 63;
    int n = blockIdx.x * 4 + pl;
    const float* fr = fin + n * H_DIM;
    float s = b1[o];
    #pragma unroll
    for (int k = 0; k < H_DIM; ++k) s = fmaf(fr[k], W1[o * H_DIM + k], s);
    s = s > 0.f ? s : 0.2f * s;
    t1s[pl][o] = s;
    __syncthreads();
    float t = b2[o];
    #pragma unroll
    for (int k = 0; k < O_DIM; ++k) t = fmaf(t1s[pl][k], W2[o * O_DIM + k], t);
    t = t > 0.f ? t : 0.2f * t;
    out[n * O_DIM + o] = t;
}

// ---------------------------------------------------------------------------
extern "C" void kernel_launch(void* const* d_in, const int* in_sizes, int n_in,
                              void* d_out, int out_size, void* d_ws, size_t ws_size,
                              hipStream_t stream)
{
    const float* points   = (const float*)d_in[0];
    const float* nuv      = (const float*)d_in[1];
    const float* features = (const float*)d_in[2];
    const float* W_in1    = (const float*)d_in[3];
    const float* b_in1    = (const float*)d_in[4];
    const float* W_in2    = (const float*)d_in[5];
    const float* b_in2    = (const float*)d_in[6];
    const float* gn_in_w  = (const float*)d_in[7];
    const float* gn_in_b  = (const float*)d_in[8];
    const float* cw1      = (const float*)d_in[9];
    const float* cb1      = (const float*)d_in[10];
    const float* cw2      = (const float*)d_in[11];
    const float* cb2      = (const float*)d_in[12];
    const float* W_out1   = (const float*)d_in[13];
    const float* b_out1   = (const float*)d_in[14];
    const float* W_out2   = (const float*)d_in[15];
    const float* b_out2   = (const float*)d_in[16];
    const float* gn_out_w = (const float*)d_in[17];
    const float* gn_out_b = (const float*)d_in[18];

    float* bufA = (float*)d_ws;                // N*64 floats
    float* bufB = bufA + N_PTS * H_DIM;        // N*64 floats
    float* outp = (float*)d_out;

    k_in_mlp    <<<N_PTS / 4, 256, 0, stream>>>(features, W_in1, b_in1, W_in2, b_in2, bufA);
    k_gnorm     <<<NGROUPS, 1024, 0, stream>>>(bufA, gn_in_w, gn_in_b, bufB);
    k_conv_mfma <<<N_PTS, 256, 0, stream>>>(points, nuv, cw1, cb1, cw2, cb2, bufB, bufA);
    k_out_mlp   <<<N_PTS / 4, 256, 0, stream>>>(bufA, W_out1, b_out1, W_out2, b_out2, bufB);
    k_gnorm     <<<NGROUPS, 1024, 0, stream>>>(bufB, gn_out_w, gn_out_b, outp);
}

// Round 6
// 220.508 us; speedup vs baseline: 2.8229x; 2.7290x over previous
//
#include <hip/hip_runtime.h>
#include <math.h>
#include <stdint.h>

#define N_PTS 2048
#define I_DIM 16
#define H_DIM 64
#define O_DIM 64
#define NCUTS 8
#define NGROUPS 4
#define GN_EPS 1e-5f
#define GN_TOT 32768.0f   // 16 ch * 2048 pts per group

typedef __attribute__((ext_vector_type(8))) short short8;
typedef __attribute__((ext_vector_type(4))) float f32x4;
typedef __attribute__((ext_vector_type(4))) uint32_t u32x4;

__device__ inline uint32_t cvt_pk_bf16(float lo, float hi) {
    uint32_t r;
    asm("v_cvt_pk_bf16_f32 %0, %1, %2" : "=v"(r) : "v"(lo), "v"(hi));
    return r;
}

__device__ inline short8 frag_of(uint32_t a, uint32_t b, uint32_t c, uint32_t d) {
    u32x4 t; t.x = a; t.y = b; t.z = c; t.w = d;
    return __builtin_bit_cast(short8, t);
}

// ---------------------------------------------------------------------------
// k_zero: zero the 16-float stats area (both group norms)
// ---------------------------------------------------------------------------
__global__ void k_zero(float* __restrict__ stats) {
    if (threadIdx.x < 16) stats[threadIdx.x] = 0.f;
}

// ---------------------------------------------------------------------------
// k_pack: pjp[j] = {x*SC, y*SC, z*SC, 0, nx, ny, nz, 0}  (32B/point)
// ---------------------------------------------------------------------------
__global__ __launch_bounds__(256) void k_pack(
    const float* __restrict__ points, const float* __restrict__ nuv,
    float* __restrict__ pjp)
{
    const float SC = 0.70710678118654752f;
    int j = blockIdx.x * 256 + threadIdx.x;
    f32x4 a, b;
    a.x = points[j * 3 + 0] * SC;
    a.y = points[j * 3 + 1] * SC;
    a.z = points[j * 3 + 2] * SC;
    a.w = 0.f;
    b.x = nuv[j * 9 + 0];
    b.y = nuv[j * 9 + 1];
    b.z = nuv[j * 9 + 2];
    b.w = 0.f;
    ((f32x4*)pjp)[j * 2 + 0] = a;
    ((f32x4*)pjp)[j * 2 + 1] = b;
}

// ---------------------------------------------------------------------------
// k1: input MLP  f = lrelu(lrelu(features @ W1^T + b1) @ W2^T + b2)
// ---------------------------------------------------------------------------
__global__ __launch_bounds__(256) void k_in_mlp(
    const float* __restrict__ features, const float* __restrict__ W1,
    const float* __restrict__ b1, const float* __restrict__ W2,
    const float* __restrict__ b2, float* __restrict__ out)
{
    __shared__ float f0s[4][H_DIM];
    int tid = threadIdx.x;
    int pl = tid >> 6, h = tid & 63;
    int n = blockIdx.x * 4 + pl;
    const float* fr = features + n * I_DIM;
    float s = b1[h];
    #pragma unroll
    for (int i = 0; i < I_DIM; ++i) s = fmaf(fr[i], W1[h * I_DIM + i], s);
    s = s > 0.f ? s : 0.2f * s;
    f0s[pl][h] = s;
    __syncthreads();
    float t = b2[h];
    #pragma unroll
    for (int k = 0; k < H_DIM; ++k) t = fmaf(f0s[pl][k], W2[h * H_DIM + k], t);
    t = t > 0.f ? t : 0.2f * t;
    out[n * H_DIM + h] = t;
}

// ---------------------------------------------------------------------------
// group-norm stats: partial sum/sumsq per group via 16-lane reduce + atomics.
// Grid stride is a multiple of 64 -> each thread's group is FIXED.
// stats[g] = sum, stats[4+g] = sumsq
// ---------------------------------------------------------------------------
__global__ __launch_bounds__(256) void k_gn_stats(
    const float* __restrict__ x, float* __restrict__ stats)
{
    int tid0 = blockIdx.x * 256 + threadIdx.x;
    int g = (tid0 >> 4) & 3;
    float s = 0.f, q = 0.f;
    for (int idx = tid0; idx < N_PTS * H_DIM; idx += gridDim.x * 256) {
        float v = x[idx];
        s += v; q += v * v;
    }
    // reduce within each 16-lane group (same g)
    #pragma unroll
    for (int off = 8; off >= 1; off >>= 1) {
        s += __shfl_xor(s, off);
        q += __shfl_xor(q, off);
    }
    if ((threadIdx.x & 15) == 0) {
        atomicAdd(&stats[g], s);
        atomicAdd(&stats[4 + g], q);
    }
}

__global__ __launch_bounds__(256) void k_gn_apply(
    const float* __restrict__ x, const float* __restrict__ stats,
    const float* __restrict__ w, const float* __restrict__ b,
    float* __restrict__ out)
{
    for (int idx = blockIdx.x * 256 + threadIdx.x; idx < N_PTS * H_DIM;
         idx += gridDim.x * 256) {
        int ch = idx & 63;
        int g = ch >> 4;
        float m = stats[g] / GN_TOT;
        float var = stats[4 + g] / GN_TOT - m * m;
        float r = rsqrtf(var + GN_EPS);
        out[idx] = (x[idx] - m) * r * w[ch] + b[ch];
    }
}

// ---------------------------------------------------------------------------
// k3: pairwise windowed conv via MFMA, LDS-staged f-tiles.
// Block = point i, 4 waves; ALL waves work the same 64-j tile (wave wv owns
// j-subtile wv*16 + l15). f-tile [64][64] double-buffered in LDS (stride 65,
// conflict-free), loaded coalesced float4, issue-early/write-late, 1 barrier
// per tile. Probed cc/jj pairing (R4-verified) for LDS reads + red writes.
// out[i,ch] = sum_j relu(D[ch,j]) * f[j][ch].
// ---------------------------------------------------------------------------
#define LDS_STRIDE 65
__global__ __launch_bounds__(256, 4) void k_conv_mfma(
    const float* __restrict__ pjp, const float* __restrict__ nuv,
    const float* __restrict__ cw1, const float* __restrict__ cb1,
    const float* __restrict__ cw2, const float* __restrict__ cb2,
    const float* __restrict__ fn, float* __restrict__ out)
{
    __shared__ float fs[2][64][LDS_STRIDE];
    __shared__ float red[4][H_DIM];

    int i   = blockIdx.x;
    int tid = threadIdx.x;
    int lane = tid & 63, wv = tid >> 6;
    int l15 = lane & 15, lg = lane >> 4;

    // ---- layout probes (verbatim from R4 — verified PASS) --------------
    uint32_t one_b = cvt_pk_bf16(1.f, 0.f);
    uint32_t idx_b = cvt_pk_bf16((float)l15, 0.f);
    short8 pIdx = frag_of(lg == 0 ? idx_b : 0u, 0u, 0u, 0u);
    short8 pOne = frag_of(lg == 0 ? one_b : 0u, 0u, 0u, 0u);
    f32x4 Dc = __builtin_amdgcn_mfma_f32_16x16x32_bf16(
        pIdx, pOne, (f32x4){0.f, 0.f, 0.f, 0.f}, 0, 0, 0);
    f32x4 Dj = __builtin_amdgcn_mfma_f32_16x16x32_bf16(
        pOne, pIdx, (f32x4){0.f, 0.f, 0.f, 0.f}, 0, 0, 0);
    int cc[4], ro[4];
    #pragma unroll
    for (int r = 0; r < 4; ++r) {
        cc[r] = (int)(Dc[r] + 0.5f);
        int jjr = (int)(Dj[r] + 0.5f);
        // LDS dword offset (within one buffer) of f[row = wv*16+jj][col = cc]
        ro[r] = (wv * 16 + jjr) * LDS_STRIDE + cc[r];
    }

    // ---- per-block (uniform) point-i data ------------------------------
    float pix = pjp[i * 8 + 0];
    float piy = pjp[i * 8 + 1];
    float piz = pjp[i * 8 + 2];
    float nv[9];
    #pragma unroll
    for (int a = 0; a < 9; ++a) nv[a] = nuv[i * 9 + a];
    float w1c[NCUTS][3], bb1[NCUTS];
    #pragma unroll
    for (int c = 0; c < NCUTS; ++c) {
        w1c[c][0] = cw1[c * 3 + 0];
        w1c[c][1] = cw1[c * 3 + 1];
        w1c[c][2] = cw1[c * 3 + 2];
        bb1[c]    = cb1[c];
    }

    // ---- constant A-frags: tile m covers ch = m*16 + (0..15) -----------
    short8 Af[4];
    #pragma unroll
    for (int m = 0; m < 4; ++m) {
        int ch = m * 16 + l15;
        uint32_t a0 = 0, a1 = 0, a2 = 0, a3 = 0;
        if (lg == 0) {
            a0 = cvt_pk_bf16(cw2[ch * 8 + 0], cw2[ch * 8 + 1]);
            a1 = cvt_pk_bf16(cw2[ch * 8 + 2], cw2[ch * 8 + 3]);
            a2 = cvt_pk_bf16(cw2[ch * 8 + 4], cw2[ch * 8 + 5]);
            a3 = cvt_pk_bf16(cw2[ch * 8 + 6], cw2[ch * 8 + 7]);
        } else if (lg == 1) {
            a0 = cvt_pk_bf16(cb2[ch], 0.f);   // k=8 slot: bias row
        }
        Af[m] = frag_of(a0, a1, a2, a3);
    }

    float acc[4][4];
    #pragma unroll
    for (int m = 0; m < 4; ++m)
        #pragma unroll
        for (int r = 0; r < 4; ++r) acc[m][r] = 0.f;

    const f32x4* fn4 = (const f32x4*)fn;   // tile jt = 1024 float4s at jt*1024
    int row0 = tid >> 4, c0 = (tid & 15) * 4;   // this thread's store slots
    float* fsf = &fs[0][0][0];

    // ---- prologue: stage tile 0 into fs[0] -----------------------------
    {
        f32x4 s0 = fn4[0 * 256 + tid];
        f32x4 s1 = fn4[1 * 256 + tid];
        f32x4 s2 = fn4[2 * 256 + tid];
        f32x4 s3 = fn4[3 * 256 + tid];
        fs[0][row0     ][c0] = s0.x; fs[0][row0     ][c0+1] = s0.y; fs[0][row0     ][c0+2] = s0.z; fs[0][row0     ][c0+3] = s0.w;
        fs[0][row0 + 16][c0] = s1.x; fs[0][row0 + 16][c0+1] = s1.y; fs[0][row0 + 16][c0+2] = s1.z; fs[0][row0 + 16][c0+3] = s1.w;
        fs[0][row0 + 32][c0] = s2.x; fs[0][row0 + 32][c0+1] = s2.y; fs[0][row0 + 32][c0+2] = s2.z; fs[0][row0 + 32][c0+3] = s2.w;
        fs[0][row0 + 48][c0] = s3.x; fs[0][row0 + 48][c0+1] = s3.y; fs[0][row0 + 48][c0+2] = s3.z; fs[0][row0 + 48][c0+3] = s3.w;
    }
    __syncthreads();

    #pragma unroll 1
    for (int jt = 0; jt < N_PTS / 64; ++jt) {
        int buf = jt & 1;
        // issue next tile's global loads EARLY (T14: issue-early/write-late)
        f32x4 s0, s1, s2, s3;
        bool havenext = (jt + 1) < (N_PTS / 64);
        if (havenext) {
            const f32x4* src = fn4 + (size_t)(jt + 1) * 1024;
            s0 = src[0 * 256 + tid];
            s1 = src[1 * 256 + tid];
            s2 = src[2 * 256 + tid];
            s3 = src[3 * 256 + tid];
        }

        // ---- compute on fs[buf]: this lane feeds j-col = wv*16 + l15 ---
        int j = jt * 64 + wv * 16 + l15;
        f32x4 pa = ((const f32x4*)pjp)[j * 2 + 0];
        f32x4 pb = ((const f32x4*)pjp)[j * 2 + 1];
        float dx = pa.x - pix;
        float dy = pa.y - piy;
        float dz = pa.z - piz;
        float nd = nv[0] * pb.x + nv[1] * pb.y + nv[2] * pb.z;
        float tt = 2.f - nd;
        float d2 = (dx * dx + dy * dy + dz * dz) * tt * tt;
        float win = __expf(-d2);
        float P0 = nv[0] * dx + nv[1] * dy + nv[2] * dz;
        float P1 = nv[3] * dx + nv[4] * dy + nv[5] * dz;
        float P2 = nv[6] * dx + nv[7] * dy + nv[8] * dz;
        float hp[NCUTS];
        #pragma unroll
        for (int c = 0; c < NCUTS; ++c) {
            float v = fmaf(P0, w1c[c][0], fmaf(P1, w1c[c][1], fmaf(P2, w1c[c][2], bb1[c])));
            v = v > 0.f ? v : 0.f;
            hp[c] = win * v;                  // fold window into B
        }
        uint32_t hw0 = cvt_pk_bf16(hp[0], hp[1]);
        uint32_t hw1 = cvt_pk_bf16(hp[2], hp[3]);
        uint32_t hw2 = cvt_pk_bf16(hp[4], hp[5]);
        uint32_t hw3 = cvt_pk_bf16(hp[6], hp[7]);
        uint32_t ww  = cvt_pk_bf16(win, 0.f);
        short8 Bf = frag_of(
            (lg == 0) ? hw0 : ((lg == 1) ? ww : 0u),
            (lg == 0) ? hw1 : 0u,
            (lg == 0) ? hw2 : 0u,
            (lg == 0) ? hw3 : 0u);
        const float* fb = fsf + buf * (64 * LDS_STRIDE);
        #pragma unroll
        for (int m = 0; m < 4; ++m) {
            f32x4 C = __builtin_amdgcn_mfma_f32_16x16x32_bf16(
                Af[m], Bf, (f32x4){0.f, 0.f, 0.f, 0.f}, 0, 0, 0);
            #pragma unroll
            for (int r = 0; r < 4; ++r) {
                float x = C[r] > 0.f ? C[r] : 0.f;
                float fval = fb[ro[r] + m * 16];
                acc[m][r] = fmaf(x, fval, acc[m][r]);
            }
        }

        // ---- write next tile into the other buffer, then one barrier ---
        if (havenext) {
            int nb = buf ^ 1;
            fs[nb][row0     ][c0] = s0.x; fs[nb][row0     ][c0+1] = s0.y; fs[nb][row0     ][c0+2] = s0.z; fs[nb][row0     ][c0+3] = s0.w;
            fs[nb][row0 + 16][c0] = s1.x; fs[nb][row0 + 16][c0+1] = s1.y; fs[nb][row0 + 16][c0+2] = s1.z; fs[nb][row0 + 16][c0+3] = s1.w;
            fs[nb][row0 + 32][c0] = s2.x; fs[nb][row0 + 32][c0+1] = s2.y; fs[nb][row0 + 32][c0+2] = s2.z; fs[nb][row0 + 32][c0+3] = s2.w;
            fs[nb][row0 + 48][c0] = s3.x; fs[nb][row0 + 48][c0+1] = s3.y; fs[nb][row0 + 48][c0+2] = s3.z; fs[nb][row0 + 48][c0+3] = s3.w;
        }
        __syncthreads();
    }

    // reduce over the 16 j-columns held across l15 (butterfly -> all lanes)
    #pragma unroll
    for (int m = 0; m < 4; ++m)
        #pragma unroll
        for (int r = 0; r < 4; ++r) {
            float v = acc[m][r];
            v += __shfl_xor(v, 1);
            v += __shfl_xor(v, 2);
            v += __shfl_xor(v, 4);
            v += __shfl_xor(v, 8);
            acc[m][r] = v;
        }

    if (l15 == 0) {
        #pragma unroll
        for (int m = 0; m < 4; ++m)
            #pragma unroll
            for (int r = 0; r < 4; ++r)
                red[wv][m * 16 + cc[r]] = acc[m][r];
    }
    __syncthreads();
    if (tid < H_DIM) {
        out[i * H_DIM + tid] = red[0][tid] + red[1][tid] + red[2][tid] + red[3][tid];
    }
}

// ---------------------------------------------------------------------------
// k4: output MLP
// ---------------------------------------------------------------------------
__global__ __launch_bounds__(256) void k_out_mlp(
    const float* __restrict__ fin, const float* __restrict__ W1,
    const float* __restrict__ b1, const float* __restrict__ W2,
    const float* __restrict__ b2, float* __restrict__ out)
{
    __shared__ float t1s[4][O_DIM];
    int tid = threadIdx.x;
    int pl = tid >> 6, o = tid & 63;
    int n = blockIdx.x * 4 + pl;
    const float* fr = fin + n * H_DIM;
    float s = b1[o];
    #pragma unroll
    for (int k = 0; k < H_DIM; ++k) s = fmaf(fr[k], W1[o * H_DIM + k], s);
    s = s > 0.f ? s : 0.2f * s;
    t1s[pl][o] = s;
    __syncthreads();
    float t = b2[o];
    #pragma unroll
    for (int k = 0; k < O_DIM; ++k) t = fmaf(t1s[pl][k], W2[o * O_DIM + k], t);
    t = t > 0.f ? t : 0.2f * t;
    out[n * O_DIM + o] = t;
}

// ---------------------------------------------------------------------------
extern "C" void kernel_launch(void* const* d_in, const int* in_sizes, int n_in,
                              void* d_out, int out_size, void* d_ws, size_t ws_size,
                              hipStream_t stream)
{
    const float* points   = (const float*)d_in[0];
    const float* nuv      = (const float*)d_in[1];
    const float* features = (const float*)d_in[2];
    const float* W_in1    = (const float*)d_in[3];
    const float* b_in1    = (const float*)d_in[4];
    const float* W_in2    = (const float*)d_in[5];
    const float* b_in2    = (const float*)d_in[6];
    const float* gn_in_w  = (const float*)d_in[7];
    const float* gn_in_b  = (const float*)d_in[8];
    const float* cw1      = (const float*)d_in[9];
    const float* cb1      = (const float*)d_in[10];
    const float* cw2      = (const float*)d_in[11];
    const float* cb2      = (const float*)d_in[12];
    const float* W_out1   = (const float*)d_in[13];
    const float* b_out1   = (const float*)d_in[14];
    const float* W_out2   = (const float*)d_in[15];
    const float* b_out2   = (const float*)d_in[16];
    const float* gn_out_w = (const float*)d_in[17];
    const float* gn_out_b = (const float*)d_in[18];

    float* bufA  = (float*)d_ws;                    // N*64
    float* pjp   = bufA + N_PTS * H_DIM;            // N*8 packed points/normals
    float* stats = pjp + N_PTS * 8;                 // 16 floats (2 group norms)
    float* bufB  = (float*)d_out;                   // reuse output buffer as scratch
    float* outp  = (float*)d_out;

    k_zero     <<<1, 64, 0, stream>>>(stats);
    k_pack     <<<N_PTS / 256, 256, 0, stream>>>(points, nuv, pjp);
    k_in_mlp   <<<N_PTS / 4, 256, 0, stream>>>(features, W_in1, b_in1, W_in2, b_in2, bufA);
    k_gn_stats <<<32, 256, 0, stream>>>(bufA, stats);
    k_gn_apply <<<256, 256, 0, stream>>>(bufA, stats, gn_in_w, gn_in_b, bufB);
    k_conv_mfma<<<N_PTS, 256, 0, stream>>>(pjp, nuv, cw1, cb1, cw2, cb2, bufB, bufA);
    k_out_mlp  <<<N_PTS / 4, 256, 0, stream>>>(bufA, W_out1, b_out1, W_out2, b_out2, bufB);
    k_gn_stats <<<32, 256, 0, stream>>>(bufB, stats + 8);
    k_gn_apply <<<256, 256, 0, stream>>>(bufB, stats + 8, gn_out_w, gn_out_b, outp);
}